// Round 5
// baseline (187.443 us; speedup 1.0000x reference)
//
#include <hip/hip_runtime.h>
#include <hip/hip_bf16.h>

#define Bsz  4096
#define Tn   256
#define CIN  16
#define NCLS 10
#define MB   16          // batch rows per recurrence block

typedef __attribute__((ext_vector_type(8))) short short8;
typedef __attribute__((ext_vector_type(4))) float f32x4;

#if __has_builtin(__builtin_amdgcn_exp2f)
#define EXP2F(x) __builtin_amdgcn_exp2f(x)
#else
#define EXP2F(x) exp2f(x)
#endif
#define RCPF(x) __builtin_amdgcn_rcpf(x)

#define LOG2E 1.442695041f

__device__ inline ushort f2bf(float f) {
    union { float f; unsigned u; } x; x.f = f;
    return (ushort)((x.u + 0x7FFF + ((x.u >> 16) & 1)) >> 16);  // RNE
}

// ================= Kernel A: recurrence (4 gate waves, logits -> ws) ========
// wave ub owns units 16ub..16ub+15. One barrier/step. Head logits for step
// t-1 (from h_{t-1} in rdb) computed redundantly per wave; wave ub stores
// acc slot reg=ub -> rows grp*4+ub. Logits layout: ws [B][T][12] f32.
__global__ __launch_bounds__(256, 1) void rec_kernel(
    const float* __restrict__ x,  const float* __restrict__ Wl, const float* __restrict__ bl,
    const float* __restrict__ Wc, const float* __restrict__ bc,
    const float* __restrict__ Wd, const float* __restrict__ bd,
    float* __restrict__ wslog)
{
    __shared__ alignas(16) ushort comb[2][16][104];  // [parity][row][k] 0..15 x,16..79 h,80..95 pad
    const int tid  = threadIdx.x;
    const int ub   = tid >> 6;       // wave id = unit block
    const int lane = tid & 63;
    const int col  = lane & 15;
    const int grp  = lane >> 4;
    const int b0   = blockIdx.x * MB;

    for (int i = tid; i < 2 * 16 * 104; i += 256) ((ushort*)comb)[i] = 0;

    // gate weights, exp2-scale folded: i,f,o -> -log2e; g -> +2*log2e
    short8 wf[4][3]; f32x4 biasv[4];
#pragma unroll
    for (int g = 0; g < 4; ++g) {
        const float sc = (g == 3) ? 2.f * LOG2E : -LOG2E;
        const int R = g * 64 + ub * 16 + col;
        const float bv = bl[R] * sc;
        biasv[g] = (f32x4){bv, bv, bv, bv};
#pragma unroll
        for (int kt = 0; kt < 3; ++kt)
#pragma unroll
            for (int i = 0; i < 8; ++i) {
                const int k = kt * 32 + grp * 8 + i;
                wf[g][kt][i] = (short)f2bf(k < 80 ? Wl[R * 80 + k] * sc : 0.f);
            }
    }
    // head weights, natural scale (softmax/sigmoid done in head_kernel)
    short8 wcd[2];
#pragma unroll
    for (int kt = 0; kt < 2; ++kt)
#pragma unroll
        for (int i = 0; i < 8; ++i) {
            const int k = kt * 32 + grp * 8 + i;
            float v = 0.f;
            if (col < 10)       v = Wc[col * 64 + k];
            else if (col == 10) v = Wd[k];
            wcd[kt][i] = (short)f2bf(v);
        }
    const float bv2 = (col < 10) ? bc[col] : ((col == 10) ? bd[0] : 0.f);
    const f32x4 bcdv = {bv2, bv2, bv2, bv2};

    __syncthreads();   // zero-fill complete
    comb[0][tid >> 4][tid & 15] =
        f2bf(x[((size_t)(b0 + (tid >> 4)) * Tn) * CIN + (tid & 15)]);
    __syncthreads();

    float cst[4] = {0, 0, 0, 0};
    const int xr = tid >> 4, xc = tid & 15;
    float xva = x[((size_t)(b0 + xr) * Tn + 1) * CIN + xc];      // x_{t+1} buffer
    const float* xp = x + ((size_t)(b0 + xr) * Tn + 2) * CIN + xc;

    const int orow = grp * 4 + ub;   // head output row for this thread
    float* lgp = wslog + ((size_t)(b0 + orow) * Tn) * 12 + col;

    for (int t = 0; t < Tn; ++t) {
        const ushort (*rdb)[104] = comb[t & 1];
        ushort (*wrb)[104] = comb[(t + 1) & 1];
        float xvn = 0.f;
        if (t + 2 < Tn) xvn = *xp;
        xp += CIN;
        const short8 a0  = *(const short8*)&rdb[col][ 0 + grp * 8];
        const short8 a1  = *(const short8*)&rdb[col][32 + grp * 8];
        const short8 a2  = *(const short8*)&rdb[col][64 + grp * 8];
        const short8 ha0 = *(const short8*)&rdb[col][16 + grp * 8];
        const short8 ha1 = *(const short8*)&rdb[col][48 + grp * 8];

        f32x4 acc[4];
#pragma unroll
        for (int g = 0; g < 4; ++g) {
            f32x4 z = biasv[g];
            z = __builtin_amdgcn_mfma_f32_16x16x32_bf16(a0, wf[g][0], z, 0, 0, 0);
            z = __builtin_amdgcn_mfma_f32_16x16x32_bf16(a1, wf[g][1], z, 0, 0, 0);
            z = __builtin_amdgcn_mfma_f32_16x16x32_bf16(a2, wf[g][2], z, 0, 0, 0);
            acc[g] = z;
        }
        f32x4 cz = bcdv;   // head logits on h_{t-1}
        cz = __builtin_amdgcn_mfma_f32_16x16x32_bf16(ha0, wcd[0], cz, 0, 0, 0);
        cz = __builtin_amdgcn_mfma_f32_16x16x32_bf16(ha1, wcd[1], cz, 0, 0, 0);

        const int hc = 16 + ub * 16 + col;
#pragma unroll
        for (int j = 0; j < 4; ++j) {
            const float ei = EXP2F(acc[0][j]);
            const float ef = EXP2F(acc[1][j]);
            const float eo = EXP2F(acc[2][j]);
            const float eg = EXP2F(acc[3][j]);
            const float A  = 1.f + ei, Bv = 1.f + ef;
            const float G1 = eg + 1.f, G2 = eg - 1.f, O = 1.f + eo;
            const float t0  = A * G1;
            const float num = cst[j] * t0 + G2 * Bv;
            const float den = Bv * t0;
            const float cn  = num * RCPF(den);
            cst[j] = cn;
            const float e2 = EXP2F(2.f * LOG2E * cn);
            const float h  = (e2 - 1.f) * RCPF((e2 + 1.f) * O);
            wrb[grp * 4 + j][hc] = f2bf(h);
        }
        if (t + 1 < Tn) wrb[xr][xc] = f2bf(xva);
        xva = xvn;
        if (t > 0) {   // logits for step t-1
            if (col < 11) {
                const float v = (ub == 0) ? cz[0] : (ub == 1) ? cz[1]
                              : (ub == 2) ? cz[2] : cz[3];
                lgp[0] = v;
            }
            lgp += 12;
        }
        __syncthreads();
    }
    // epilogue: logits for step Tn-1 from h_{Tn-1} in comb[Tn&1]
    {
        const ushort (*rdb)[104] = comb[Tn & 1];
        const short8 ha0 = *(const short8*)&rdb[col][16 + grp * 8];
        const short8 ha1 = *(const short8*)&rdb[col][48 + grp * 8];
        f32x4 cz = bcdv;
        cz = __builtin_amdgcn_mfma_f32_16x16x32_bf16(ha0, wcd[0], cz, 0, 0, 0);
        cz = __builtin_amdgcn_mfma_f32_16x16x32_bf16(ha1, wcd[1], cz, 0, 0, 0);
        if (col < 11) {
            const float v = (ub == 0) ? cz[0] : (ub == 1) ? cz[1]
                          : (ub == 2) ? cz[2] : cz[3];
            lgp[0] = v;
        }
    }
}

// ================= Kernel B: streaming softmax / dec ========================
__global__ __launch_bounds__(256) void head_kernel(
    const float* __restrict__ wslog, float* __restrict__ out, float* __restrict__ dec)
{
    const size_t r = (size_t)blockIdx.x * 256 + threadIdx.x;   // (b,t) row
    const float4* lg = (const float4*)(wslog + r * 12);
    const float4 v0 = lg[0], v1 = lg[1], v2 = lg[2];   // cols 0-3,4-7,8-11
    const float e0 = EXP2F(v0.x * LOG2E), e1 = EXP2F(v0.y * LOG2E);
    const float e2 = EXP2F(v0.z * LOG2E), e3 = EXP2F(v0.w * LOG2E);
    const float e4 = EXP2F(v1.x * LOG2E), e5 = EXP2F(v1.y * LOG2E);
    const float e6 = EXP2F(v1.z * LOG2E), e7 = EXP2F(v1.w * LOG2E);
    const float e8 = EXP2F(v2.x * LOG2E), e9 = EXP2F(v2.y * LOG2E);
    const float s = ((e0 + e1) + (e2 + e3)) + ((e4 + e5) + (e6 + e7)) + (e8 + e9);
    const float lse = __logf(s);
    float* lp = out + r * 10;   // 8B-aligned (40B stride)
    ((float2*)lp)[0] = (float2){v0.x - lse, v0.y - lse};
    ((float2*)lp)[1] = (float2){v0.z - lse, v0.w - lse};
    ((float2*)lp)[2] = (float2){v1.x - lse, v1.y - lse};
    ((float2*)lp)[3] = (float2){v1.z - lse, v1.w - lse};
    ((float2*)lp)[4] = (float2){v2.x - lse, v2.y - lse};
    dec[r] = RCPF(1.f + EXP2F(-v2.z * LOG2E));   // sigmoid(logit_dec)
}

// ================= Kernel C: pnd scan ======================================
__global__ __launch_bounds__(64) void pnd_kernel(
    const float* __restrict__ dec, float* __restrict__ pt)
{
    __shared__ float tile[64][65];
    const int ln = threadIdx.x;
    const int b0 = blockIdx.x * 64;
    float pnd = 1.f;
    for (int tc = 0; tc < Tn; tc += 64) {
#pragma unroll 8
        for (int i = 0; i < 64; ++i)   // coalesced loads, transposed into LDS
            tile[i][ln] = dec[(size_t)(b0 + i) * Tn + tc + ln];
        __syncthreads();
        for (int tl = 0; tl < 64; ++tl) {   // serial scan over own row b0+ln
            const float d = tile[ln][tl];
            float v = d * pnd;
            if (tc + tl == Tn - 1) v = pnd;   // last step: Pt = pnd before update
            tile[ln][tl] = v;
            pnd *= (1.f - d);
        }
        __syncthreads();
        float* dst = pt + (size_t)(b0 + ln) * Tn + tc;
#pragma unroll 8
        for (int k = 0; k < 64; ++k) dst[k] = tile[ln][k];
        __syncthreads();
    }
}

// ================= Fallback: R3 fused kernel (ws too small) =================
__global__ __launch_bounds__(512, 2) void dualrnn_fused(
    const float* __restrict__ x,  const float* __restrict__ Wl, const float* __restrict__ bl,
    const float* __restrict__ Wc, const float* __restrict__ bc,
    const float* __restrict__ Wd, const float* __restrict__ bd,
    float* __restrict__ out)
{
    __shared__ alignas(16) ushort comb[2][16][104];
    const int tid  = threadIdx.x;
    const int wave = tid >> 6;
    const int lane = tid & 63;
    const int col  = lane & 15;
    const int grp  = lane >> 4;
    const int b0   = blockIdx.x * MB;
    const bool gatew = (wave < 4);

    for (int i = tid; i < 2 * 16 * 104; i += 512) ((ushort*)comb)[i] = 0;

    short8 wf[4][3]; f32x4 biasv[4];
    short8 wcd[2];   f32x4 bcdv;
    if (gatew) {
#pragma unroll
        for (int g = 0; g < 4; ++g) {
            const float sc = (g == 3) ? 2.f * LOG2E : -LOG2E;
            const int R = g * 64 + wave * 16 + col;
            const float bv = bl[R] * sc;
            biasv[g] = (f32x4){bv, bv, bv, bv};
#pragma unroll
            for (int kt = 0; kt < 3; ++kt)
#pragma unroll
                for (int i = 0; i < 8; ++i) {
                    const int k = kt * 32 + grp * 8 + i;
                    wf[g][kt][i] = (short)f2bf(k < 80 ? Wl[R * 80 + k] * sc : 0.f);
                }
        }
    } else {
#pragma unroll
        for (int kt = 0; kt < 2; ++kt)
#pragma unroll
            for (int i = 0; i < 8; ++i) {
                const int k = kt * 32 + grp * 8 + i;
                float v = 0.f;
                if (col < 10)       v = Wc[col * 64 + k];
                else if (col == 10) v = Wd[k] * -LOG2E;
                wcd[kt][i] = (short)f2bf(v);
            }
        const float bv = (col < 10) ? bc[col] : ((col == 10) ? bd[0] * -LOG2E : 0.f);
        bcdv = (f32x4){bv, bv, bv, bv};
    }
    __syncthreads();
    if (tid < 256) {
        const int r = tid >> 4, ch = tid & 15;
        comb[0][r][ch] = f2bf(x[((size_t)(b0 + r) * Tn) * CIN + ch]);
    }
    __syncthreads();

    float cst[4] = {0, 0, 0, 0};
    float pnd = 1.f;
    const int hw  = wave & 3;
    const int row = grp * 4 + hw;
    float* lp_p = out + ((size_t)(b0 + row) * Tn) * NCLS + col;
    float* pt_p = out + (size_t)Bsz * Tn * NCLS + (size_t)(b0 + row) * Tn;
    const int t2 = hw * 64 + lane;
    const int xr = t2 >> 4, xc = t2 & 15;
    float xva = 0.f;
    const float* xp = x + ((size_t)(b0 + xr) * Tn + 2) * CIN + xc;
    if (!gatew) xva = x[((size_t)(b0 + xr) * Tn + 1) * CIN + xc];

    for (int t = 0; t < Tn; ++t) {
        const ushort (*rdb)[104] = comb[t & 1];
        ushort (*wrb)[104] = comb[(t + 1) & 1];
        if (gatew) {
            const short8 a0 = *(const short8*)&rdb[col][ 0 + grp * 8];
            const short8 a1 = *(const short8*)&rdb[col][32 + grp * 8];
            const short8 a2 = *(const short8*)&rdb[col][64 + grp * 8];
            f32x4 acc[4];
#pragma unroll
            for (int g = 0; g < 4; ++g) {
                f32x4 z = biasv[g];
                z = __builtin_amdgcn_mfma_f32_16x16x32_bf16(a0, wf[g][0], z, 0, 0, 0);
                z = __builtin_amdgcn_mfma_f32_16x16x32_bf16(a1, wf[g][1], z, 0, 0, 0);
                z = __builtin_amdgcn_mfma_f32_16x16x32_bf16(a2, wf[g][2], z, 0, 0, 0);
                acc[g] = z;
            }
            const int hc = 16 + wave * 16 + col;
#pragma unroll
            for (int j = 0; j < 4; ++j) {
                const float ei = EXP2F(acc[0][j]);
                const float ef = EXP2F(acc[1][j]);
                const float eo = EXP2F(acc[2][j]);
                const float eg = EXP2F(acc[3][j]);
                const float A  = 1.f + ei, Bv = 1.f + ef;
                const float G1 = eg + 1.f, G2 = eg - 1.f, O = 1.f + eo;
                const float t0  = A * G1;
                const float num = cst[j] * t0 + G2 * Bv;
                const float den = Bv * t0;
                const float cn  = num * RCPF(den);
                cst[j] = cn;
                const float e2 = EXP2F(2.f * LOG2E * cn);
                const float h  = (e2 - 1.f) * RCPF((e2 + 1.f) * O);
                wrb[grp * 4 + j][hc] = f2bf(h);
            }
        } else {
            float xvn = 0.f;
            if (t + 2 < Tn) xvn = *xp;
            xp += CIN;
            const short8 ha0 = *(const short8*)&rdb[col][16 + grp * 8];
            const short8 ha1 = *(const short8*)&rdb[col][48 + grp * 8];
            f32x4 cz = bcdv;
            cz = __builtin_amdgcn_mfma_f32_16x16x32_bf16(ha0, wcd[0], cz, 0, 0, 0);
            cz = __builtin_amdgcn_mfma_f32_16x16x32_bf16(ha1, wcd[1], cz, 0, 0, 0);
            if (t + 1 < Tn) wrb[xr][xc] = f2bf(xva);
            xva = xvn;
            if (t > 0) {
                float v = (hw & 1) ? ((hw & 2) ? cz[3] : cz[1])
                                   : ((hw & 2) ? cz[2] : cz[0]);
                float s = (col < 10) ? EXP2F(v * LOG2E) : 0.f;
                s += __int_as_float(__builtin_amdgcn_ds_swizzle(__float_as_int(s), 0x041F));
                s += __int_as_float(__builtin_amdgcn_ds_swizzle(__float_as_int(s), 0x081F));
                s += __int_as_float(__builtin_amdgcn_ds_swizzle(__float_as_int(s), 0x101F));
                s += __int_as_float(__builtin_amdgcn_ds_swizzle(__float_as_int(s), 0x201F));
                const float lse = __logf(s);
                if (col < 10) {
                    lp_p[0] = v - lse;
                } else if (col == 10) {
                    const float d = RCPF(1.f + EXP2F(v));
                    pt_p[0] = d * pnd;
                    pnd *= (1.f - d);
                }
                lp_p += NCLS;
                pt_p += 1;
            }
        }
        __syncthreads();
    }
    if (!gatew) {
        const ushort (*rdb)[104] = comb[Tn & 1];
        const short8 ha0 = *(const short8*)&rdb[col][16 + grp * 8];
        const short8 ha1 = *(const short8*)&rdb[col][48 + grp * 8];
        f32x4 cz = bcdv;
        cz = __builtin_amdgcn_mfma_f32_16x16x32_bf16(ha0, wcd[0], cz, 0, 0, 0);
        cz = __builtin_amdgcn_mfma_f32_16x16x32_bf16(ha1, wcd[1], cz, 0, 0, 0);
        float v = (hw & 1) ? ((hw & 2) ? cz[3] : cz[1])
                           : ((hw & 2) ? cz[2] : cz[0]);
        float s = (col < 10) ? EXP2F(v * LOG2E) : 0.f;
        s += __int_as_float(__builtin_amdgcn_ds_swizzle(__float_as_int(s), 0x041F));
        s += __int_as_float(__builtin_amdgcn_ds_swizzle(__float_as_int(s), 0x081F));
        s += __int_as_float(__builtin_amdgcn_ds_swizzle(__float_as_int(s), 0x101F));
        s += __int_as_float(__builtin_amdgcn_ds_swizzle(__float_as_int(s), 0x201F));
        const float lse = __logf(s);
        if (col < 10)       lp_p[0] = v - lse;
        else if (col == 10) pt_p[0] = pnd;
    }
}

extern "C" void kernel_launch(void* const* d_in, const int* in_sizes, int n_in,
                              void* d_out, int out_size, void* d_ws, size_t ws_size,
                              hipStream_t stream) {
    const float* x  = (const float*)d_in[0];
    const float* Wl = (const float*)d_in[1];
    const float* bl = (const float*)d_in[2];
    const float* Wc = (const float*)d_in[3];
    const float* bc = (const float*)d_in[4];
    const float* Wd = (const float*)d_in[5];
    const float* bd = (const float*)d_in[6];
    float* out = (float*)d_out;

    const size_t logN = (size_t)Bsz * Tn * 12;               // logits f32
    const size_t decN = (size_t)Bsz * Tn;                    // dec f32
    const size_t need = (logN + decN) * sizeof(float);

    if (ws_size >= need) {
        float* wslog = (float*)d_ws;
        float* dec   = wslog + logN;
        hipLaunchKernelGGL(rec_kernel, dim3(Bsz / MB), dim3(256), 0, stream,
                           x, Wl, bl, Wc, bc, Wd, bd, wslog);
        hipLaunchKernelGGL(head_kernel, dim3((Bsz * Tn) / 256), dim3(256), 0, stream,
                           wslog, out, dec);
        hipLaunchKernelGGL(pnd_kernel, dim3(Bsz / 64), dim3(64), 0, stream,
                           dec, out + (size_t)Bsz * Tn * NCLS);
    } else {
        hipLaunchKernelGGL(dualrnn_fused, dim3(Bsz / MB), dim3(512), 0, stream,
                           x, Wl, bl, Wc, bc, Wd, bd, out);
    }
}